// Round 5
// baseline (252.133 us; speedup 1.0000x reference)
//
#include <hip/hip_runtime.h>

// Embedding gather: out[b,t,:] = W[:, tokens[b,t]] + bias
//   tokens: [16384] i32, W: [768, 50257] f32 row-major, bias: [768], out: [16384, 768]
//
// Ladder: R2 arrival-order 766MB/256us -> R3 vocab-sorted 76MB/97us (L3-request
// bound) -> R4 transposed wave layout (~13 lines/instr) ~70us but VGPR=12 ->
// serial loads. R5: forced MLP=16 (split load/use loops), 64x64 tile (17.7KB
// LDS -> 32 waves/CU), f32x4 LDS+stores, single-dispatch fused prepass.
//
// ws: [0,4096) unused now except pairs region: pairs at offset 16KB, [16384] u32.

constexpr int V    = 50257;
constexpr int E    = 768;
constexpr int NTOK = 8 * 2048;           // 16384
constexpr int NBP  = 4096;               // buckets of 16 vocab entries (padded)

typedef float f32x4 __attribute__((ext_vector_type(4)));

// --- K1: fused prepass (zero + histogram + scan + scatter), ONE block ---
__global__ __launch_bounds__(1024) void prepass_kernel(const int* __restrict__ tokens,
                                                       unsigned* __restrict__ pairs) {
    __shared__ int cnt[NBP];
    __shared__ int wtot[16];
    int tid = threadIdx.x, lane = tid & 63, wid = tid >> 6;

#pragma unroll
    for (int i = 0; i < 4; ++i) cnt[tid * 4 + i] = 0;
    __syncthreads();

    int tk[16];
#pragma unroll
    for (int i = 0; i < 16; ++i) tk[i] = tokens[tid + i * 1024];   // coalesced
#pragma unroll
    for (int i = 0; i < 16; ++i) atomicAdd(&cnt[tk[i] >> 4], 1);
    __syncthreads();

    // exclusive scan of cnt[4096]: 4 elems/thread -> wave scan -> 16 wave totals
    int b0 = cnt[tid * 4 + 0], b1 = cnt[tid * 4 + 1],
        b2 = cnt[tid * 4 + 2], b3 = cnt[tid * 4 + 3];
    int s = b0 + b1 + b2 + b3;
    int incl = s;
#pragma unroll
    for (int d = 1; d < 64; d <<= 1) {
        int o = __shfl_up(incl, d);
        if (lane >= d) incl += o;
    }
    int excl = incl - s;
    if (lane == 63) wtot[wid] = incl;
    __syncthreads();
    if (tid == 0) {
        int run = 0;
#pragma unroll
        for (int i = 0; i < 16; ++i) { int x = wtot[i]; wtot[i] = run; run += x; }
    }
    __syncthreads();
    int p = wtot[wid] + excl;
    cnt[tid * 4 + 0] = p;       p += b0;
    cnt[tid * 4 + 1] = p;       p += b1;
    cnt[tid * 4 + 2] = p;       p += b2;
    cnt[tid * 4 + 3] = p;
    __syncthreads();

    // scatter into vocab-sorted pair array (cnt doubles as cursor)
#pragma unroll
    for (int i = 0; i < 16; ++i) {
        int t   = tid + i * 1024;
        int pos = atomicAdd(&cnt[tk[i] >> 4], 1);
        pairs[pos] = ((unsigned)t << 16) | (unsigned)tk[i];  // t<2^14, tok<2^16
    }
}

// --- K2: transposed gather, 64 matches x 64 e-dims per block ---
constexpr int MBX  = 64;                  // sorted matches per block (lane dim)
constexpr int EC   = 64;                  // e-dims per block
constexpr int NEB  = E / EC;              // 12
constexpr int GRID = (NTOK / MBX) * NEB;  // 3072 (divisible by 8)
constexpr int CPX  = GRID / 8;            // 384 blocks per XCD chunk
constexpr int PAD  = 68;                  // row stride (floats): 272B, 16B-aligned

__global__ __launch_bounds__(256) void gather_t_kernel(
    const unsigned* __restrict__ pairs,
    const float*    __restrict__ W,
    const float*    __restrict__ bias,
    float*          __restrict__ out)
{
    __shared__ float    lds[MBX * PAD];
    __shared__ unsigned prs[MBX];

    int bid  = blockIdx.x;
    int lb   = (bid & 7) * CPX + (bid >> 3);      // XCD-chunked swizzle
    int mblk = lb / NEB, eblk = lb - mblk * NEB;
    int m0   = mblk * MBX, e0 = eblk * EC;

    int tid = threadIdx.x, lane = tid & 63, w = tid >> 6;
    if (tid < MBX) prs[tid] = pairs[m0 + tid];

    // per-thread bias fragment for the write phase
    f32x4 bvec = *(const f32x4*)(bias + e0 + (lane & 15) * 4);
    __syncthreads();

    int tok = (int)(prs[lane] & 0xFFFFu);

    // read phase: wave w owns e-rows e0+w*16 .. +15; lanes = 64 consecutive
    // sorted matches (~13 cache lines/instr). Split load/use -> MLP=16.
    const float* wp = W + (size_t)(e0 + w * 16) * V + tok;
    float v[16];
#pragma unroll
    for (int i = 0; i < 16; ++i) v[i] = wp[(size_t)i * V];

    f32x4* dst = (f32x4*)&lds[lane * PAD + w * 16];
#pragma unroll
    for (int i4 = 0; i4 < 4; ++i4) {
        f32x4 q = { v[i4 * 4 + 0], v[i4 * 4 + 1], v[i4 * 4 + 2], v[i4 * 4 + 3] };
        dst[i4] = q;   // b128, stride-68 rows: uniform 8-per-bank, conflict-free
    }
    __syncthreads();

    // write phase: 4 rows per b128 instr (16-lane groups), coalesced 256B runs
#pragma unroll
    for (int r4 = 0; r4 < 4; ++r4) {
        int row = w * 16 + r4 * 4 + (lane >> 4);
        int t   = (int)(prs[row] >> 16);
        f32x4 val = *(const f32x4*)&lds[row * PAD + (lane & 15) * 4];
        val += bvec;
        __builtin_nontemporal_store(
            val, (f32x4*)(out + (size_t)t * E + e0) + (lane & 15));
    }
}

extern "C" void kernel_launch(void* const* d_in, const int* in_sizes, int n_in,
                              void* d_out, int out_size, void* d_ws, size_t ws_size,
                              hipStream_t stream) {
    const int*   tokens = (const int*)  d_in[0];
    const float* W      = (const float*)d_in[1];
    const float* bias   = (const float*)d_in[2];
    float*       out    = (float*)      d_out;

    unsigned* pairs = (unsigned*)((char*)d_ws + NBP * sizeof(int));

    prepass_kernel <<<1, 1024, 0, stream>>>(tokens, pairs);
    gather_t_kernel<<<GRID, 256, 0, stream>>>(pairs, W, bias, out);
}